// Round 9
// baseline (159.625 us; speedup 1.0000x reference)
//
#include <hip/hip_runtime.h>

// ---------------------------------------------------------------------------
// Gate_16501264351574: conv3x3(256ch -> 64 experts) + sigmoid + top8 + softmax
//   x: [16,256,64,64] f32, gate_w: [64,256,3,3] f32, bias: [64] f32
// out (flat f32): weights [16,8,64,64] | indices-as-f32 [16,8,64,64] | counts[64]
//
// R9: occupancy over ILP. R5/R8 proved the compiler sinks register pipelines
// (VGPR 48-64); so: simple 2-barrier chunk loop, small LDS (17.9KB), cap 85
// VGPR via launch_bounds(256,6) -> 6 blocks/CU = 24 waves/CU hide latency.
// Counts via plain-store per-block hist + tiny reduce kernel (no global
// atomic convoy: R8 had 65536 device atomics onto 4 cache lines).
// ---------------------------------------------------------------------------

typedef _Float16 half8 __attribute__((ext_vector_type(8)));
typedef __attribute__((ext_vector_type(4))) float f32x4;

#define LOG2E 1.44269504f

__device__ __forceinline__ unsigned short f2h_bits(float f) {
    _Float16 h = (_Float16)f;                  // v_cvt_f16_f32, RNE
    unsigned short b;
    __builtin_memcpy(&b, &h, 2);
    return b;
}

constexpr int WB_U4 = 8 * 9 * 4 * 64;          // 18432 uint4 = 294912 B

// ---------------------------------------------------------------------------
// Prep: gate_w -> f16 B-fragments, chunk-major:
//   wB_u4[((q*9 + t)*4 + nt)*64 + lane]: e = nt*16+(lane&15), c = q*32+(lane>>4)*8+j
// ---------------------------------------------------------------------------
__global__ __launch_bounds__(256) void gate_prep(const float* __restrict__ gw,
                                                 unsigned short* __restrict__ wB) {
    int g = blockIdx.x * 256 + threadIdx.x;
    if (g >= WB_U4) return;
    int lane = g & 63;
    int nt   = (g >> 6) & 3;
    int rest = g >> 8;                          // q*9 + t
    int t = rest % 9, q = rest / 9;
    int e  = nt * 16 + (lane & 15);
    int c0 = q * 32 + (lane >> 4) * 8;
    unsigned short o[8];
#pragma unroll
    for (int j = 0; j < 8; ++j)
        o[j] = f2h_bits(gw[(e * 256 + c0 + j) * 9 + t]);
    uint4 pk;
    pk.x = (unsigned)o[0] | ((unsigned)o[1] << 16);
    pk.y = (unsigned)o[2] | ((unsigned)o[3] << 16);
    pk.z = (unsigned)o[4] | ((unsigned)o[5] << 16);
    pk.w = (unsigned)o[6] | ((unsigned)o[7] << 16);
    ((uint4*)wB)[g] = pk;
}

// ---------------------------------------------------------------------------
// Main. Grid 1024 x 256 thr: b = blk&15 (image -> XCD), r = blk>>4 (row).
// Wave rw: ph = rw>>1 (pos half), eh = rw&1 (expert half); tile 32x32.
// LDS: union{ xs [3][66][40] f16 (15840B), scf [64][68] f32 (17408B) }
//      + bias(256) + hist(256) = 17920 B -> 6+ blocks/CU at cap-85 VGPR.
// ---------------------------------------------------------------------------
constexpr int CSTR  = 40;                      // shorts per (row,w') site
constexpr int SSTR  = 68;                      // fp32 score row stride
constexpr int UNI_B = 64 * SSTR * 4;           // 17408 B

__global__ __launch_bounds__(256, 6) void gate_main(
    const float* __restrict__ x, const float* __restrict__ bias,
    const unsigned short* __restrict__ wB, float* __restrict__ out,
    float* __restrict__ ws_hist) {
    __shared__ unsigned char smem[UNI_B + 512];
    unsigned short* xs     = (unsigned short*)smem;   // [3][66][40] f16
    float*          scf    = (float*)smem;            // [64][68] f32 (alias)
    float*          bias_s = (float*)(smem + UNI_B);
    int*            hist   = (int*)(smem + UNI_B + 256);

    const int tid  = threadIdx.x;
    const int lane = tid & 63;
    const int rw   = tid >> 6;
    const int blk  = blockIdx.x;
    const int b    = blk & 15;
    const int r    = blk >> 4;                 // output row 0..63

    if (tid < 64) { bias_s[tid] = bias[tid]; hist[tid] = 0; }

    // ---- staging task descriptors (4 tasks/thread, precomputed) -----------
    // Task T = tid + i*256, T < 792 = 198 sites x 4 channel-groups(8ch).
    // T -> chh = T/198 (8-ch group), s = T%198 -> row=s/66, w'=s%66.
    bool tEx[4], tOk[4];
    int  tSrc[4], tDst[4];
#pragma unroll
    for (int i = 0; i < 4; ++i) {
        int T = tid + i * 256;
        tEx[i] = (T < 792);
        int chh = T / 198, s = T - chh * 198;
        int row2 = s / 66, wp = s - row2 * 66;
        int gr = r - 1 + row2, gwc = wp - 1;
        tOk[i]  = tEx[i] && (gr >= 0) && (gr < 64) && (gwc >= 0) && (gwc < 64);
        tSrc[i] = ((b * 256 + chh * 8) * 64 + gr) * 64 + gwc;   // + q*131072
        tDst[i] = (row2 * 66 + wp) * CSTR + chh * 8;            // shorts
    }

    const int ph = rw >> 1, eh = rw & 1;

    f32x4 acc[2][2];
#pragma unroll
    for (int mt = 0; mt < 2; ++mt)
#pragma unroll
        for (int nt = 0; nt < 2; ++nt) acc[mt][nt] = (f32x4){0.f, 0.f, 0.f, 0.f};

    // ---- K loop: 8 chunks of 32 channels; 2 barriers/chunk (m90 style) ----
#pragma unroll 1
    for (int q = 0; q < 8; ++q) {
        __syncthreads();                       // previous compute done reading xs
        // stage chunk q: 4 tasks, straight-line (24 waves/CU hide latency)
#pragma unroll
        for (int i = 0; i < 4; ++i) {
            float tb[8];
            if (tOk[i]) {
                const float* p = x + tSrc[i] + q * 131072;
#pragma unroll
                for (int u = 0; u < 8; ++u) tb[u] = p[u * 4096];
            } else {
#pragma unroll
                for (int u = 0; u < 8; ++u) tb[u] = 0.f;
            }
            if (tEx[i]) {
                uint4 pk;
                pk.x = (unsigned)f2h_bits(tb[0]) | ((unsigned)f2h_bits(tb[1]) << 16);
                pk.y = (unsigned)f2h_bits(tb[2]) | ((unsigned)f2h_bits(tb[3]) << 16);
                pk.z = (unsigned)f2h_bits(tb[4]) | ((unsigned)f2h_bits(tb[5]) << 16);
                pk.w = (unsigned)f2h_bits(tb[6]) | ((unsigned)f2h_bits(tb[7]) << 16);
                *(uint4*)(xs + tDst[i]) = pk;
            }
        }
        __syncthreads();                       // slab ready

#pragma unroll
        for (int t = 0; t < 9; ++t) {
            const int kh = t / 3, kw = t % 3;
            const unsigned short* abase =
                xs + (kh * 66 + ph * 32 + (lane & 15) + kw) * CSTR + (lane >> 4) * 8;
            half8 a0 = *(const half8*)(abase);
            half8 a1 = *(const half8*)(abase + 16 * CSTR);
            const uint4* bp =
                (const uint4*)wB + ((q * 9 + t) * 4 + eh * 2) * 64 + lane;
            uint4 bu0 = bp[0], bu1 = bp[64];
            half8 b0, b1;
            __builtin_memcpy(&b0, &bu0, 16);
            __builtin_memcpy(&b1, &bu1, 16);
            acc[0][0] = __builtin_amdgcn_mfma_f32_16x16x32_f16(a0, b0, acc[0][0], 0, 0, 0);
            acc[1][0] = __builtin_amdgcn_mfma_f32_16x16x32_f16(a1, b0, acc[1][0], 0, 0, 0);
            acc[0][1] = __builtin_amdgcn_mfma_f32_16x16x32_f16(a0, b1, acc[0][1], 0, 0, 0);
            acc[1][1] = __builtin_amdgcn_mfma_f32_16x16x32_f16(a1, b1, acc[1][1], 0, 0, 0);
        }
    }

    // ---- epilogue: sigmoid -> fp32 scores in LDS (aliases xs) -------------
    __syncthreads();                           // all waves done reading xs
#pragma unroll
    for (int mt = 0; mt < 2; ++mt)
#pragma unroll
        for (int nt = 0; nt < 2; ++nt)
#pragma unroll
            for (int rr = 0; rr < 4; ++rr) {
                float v = acc[mt][nt][rr];
                float s = 1.f / (1.f + __builtin_amdgcn_exp2f(-v * LOG2E));
                int p = ph * 32 + mt * 16 + ((lane >> 4) << 2) + rr;
                int e = eh * 32 + nt * 16 + (lane & 15);
                scf[p * SSTR + e] = s;
            }
    __syncthreads();

    if (tid < 64) {
        // top-8 of 64; jax tie-break (lower idx first): ascending scan + strict >
        const float* row = scf + tid * SSTR;
        float tv[8];
        int   ti[8];
#pragma unroll
        for (int k = 0; k < 8; ++k) { tv[k] = -3.0e38f; ti[k] = 0; }
#pragma unroll
        for (int j4 = 0; j4 < 16; ++j4) {
            f32x4 blkv = *(const f32x4*)(row + j4 * 4);
#pragma unroll
            for (int j = 0; j < 4; ++j) {
                int   e  = j4 * 4 + j;
                float bs = blkv[j] + bias_s[e];
                if (bs > tv[7]) {
                    tv[7] = bs; ti[7] = e;
#pragma unroll
                    for (int k = 7; k > 0; --k) {
                        float fa = tv[k - 1], fb = tv[k];
                        int   ia = ti[k - 1], ib = ti[k];
                        bool  sw = fb > fa;
                        tv[k - 1] = sw ? fb : fa; tv[k] = sw ? fa : fb;
                        ti[k - 1] = sw ? ib : ia; ti[k] = sw ? ia : ib;
                    }
                }
            }
        }
        // softmax over UNbiased scores of the selected 8
        float u[8], mx = -3.0e38f;
#pragma unroll
        for (int k = 0; k < 8; ++k) { u[k] = tv[k] - bias_s[ti[k]]; mx = fmaxf(mx, u[k]); }
        float ex[8], sum = 0.f;
#pragma unroll
        for (int k = 0; k < 8; ++k) { ex[k] = __builtin_amdgcn_exp2f((u[k] - mx) * LOG2E); sum += ex[k]; }
        float inv = 1.f / sum;

        int obase = b * 32768 + r * 64 + tid;  // [b][k][h=r][w=tid]
#pragma unroll
        for (int k = 0; k < 8; ++k) {
            out[obase + k * 4096]          = ex[k] * inv;     // weights
            out[524288 + obase + k * 4096] = (float)ti[k];    // indices (as f32)
            atomicAdd(&hist[ti[k]], 1);                       // LDS only
        }
    }
    __syncthreads();
    if (tid < 64) ws_hist[blk * 64 + tid] = (float)hist[tid]; // plain store
}

// ---------------------------------------------------------------------------
// Counts reduce: sum ws_hist[1024][64] -> out[1048576..+64]. One block.
// ---------------------------------------------------------------------------
__global__ __launch_bounds__(256) void gate_cnt(const float* __restrict__ ws_hist,
                                                float* __restrict__ out) {
    __shared__ float red[256];
    const int t = threadIdx.x;
    const int e = t & 63, part = t >> 6;       // 4 partial sums per expert
    float s0 = 0.f, s1 = 0.f, s2 = 0.f, s3 = 0.f, s4 = 0.f, s5 = 0.f, s6 = 0.f, s7 = 0.f;
    const float* base = ws_hist + (size_t)part * 256 * 64 + e;
#pragma unroll 1
    for (int i = 0; i < 256; i += 8) {         // 8 independent chains (MLP)
        s0 += base[(i + 0) * 64]; s1 += base[(i + 1) * 64];
        s2 += base[(i + 2) * 64]; s3 += base[(i + 3) * 64];
        s4 += base[(i + 4) * 64]; s5 += base[(i + 5) * 64];
        s6 += base[(i + 6) * 64]; s7 += base[(i + 7) * 64];
    }
    red[t] = ((s0 + s1) + (s2 + s3)) + ((s4 + s5) + (s6 + s7));
    __syncthreads();
    if (t < 64)
        out[1048576 + t] = (red[t] + red[t + 64]) + (red[t + 128] + red[t + 192]);
}

// ---------------------------------------------------------------------------
extern "C" void kernel_launch(void* const* d_in, const int* in_sizes, int n_in,
                              void* d_out, int out_size, void* d_ws, size_t ws_size,
                              hipStream_t stream) {
    const float* x    = (const float*)d_in[0];
    const float* gw   = (const float*)d_in[1];
    const float* bias = (const float*)d_in[2];
    float* out = (float*)d_out;
    unsigned short* wB = (unsigned short*)d_ws;               // 294912 B
    float* ws_hist = (float*)((char*)d_ws + 294912);          // 262144 B

    gate_prep<<<72, 256, 0, stream>>>(gw, wB);
    gate_main<<<1024, 256, 0, stream>>>(x, bias, wB, out, ws_hist);
    gate_cnt<<<1, 256, 0, stream>>>(ws_hist, out);
}